// Round 15
// baseline (507.199 us; speedup 1.0000x reference)
//
#include <hip/hip_runtime.h>

// Problem constants (from reference)
#define NLOC 10000
#define NST  168
#define NED  10000
#define NTOK 8192      // B*S = 64*128
#define SEQ  128
#define DL   128
#define DST  64
#define DED  64
#define DSUM 256
#define MAXNZ 192      // row nnz ~ Poisson(10)+1; huge margin
#define ROW4 (NLOC/4)  // 2500 float4 per 40KB fp32 row

// R15: RESOLVED. Inputs are dict-ordered fp32/int32 (loc,st,ed,A,W,bias,
// emb_st,emb_ed) -- proven by R13/R14 allocation-fault geometry + R7 dtype
// probes. The 14-round failure cause: the OUTPUT buffer is fp32 (checker's
// float32 branch), not bf16 -- proven by R11/R12 probe-vanishing (u16 probe
// landed as an fp32 denormal) and the pairwise-packing error signatures
// (R1 1.9336 / R3 5.6e36 / R12 1.5625). This kernel = R1's wiring, fp32 out.

__device__ __forceinline__ int clampi(int v, int hi) {
    return v < 0 ? 0 : (v >= hi ? hi - 1 : v);
}

__global__ __launch_bounds__(256) void fused_kernel(const int* __restrict__ loc_p,
                                                    const int* __restrict__ st_p,
                                                    const int* __restrict__ ed_p,
                                                    const float* __restrict__ A,
                                                    const float* __restrict__ W,
                                                    const float* __restrict__ bias,
                                                    const float* __restrict__ emb_st,
                                                    const float* __restrict__ emb_ed,
                                                    float* __restrict__ out) {
    const int t   = blockIdx.x;
    const int tid = threadIdx.x;
    const int s   = t & (SEQ - 1);
    const int loc_t = clampi(loc_p[t], NLOC);
    const int st_t  = clampi(st_p[t],  NST);
    const int ed_t  = clampi(ed_p[t],  NED);
    const int yt_t  = (s < SEQ - 1) ? clampi(st_p[t + 1], NST) : 0;  // 0-padded

    // ---- sparse scan of A[loc_t] (row-major, 40000B offset, 16B aligned) ----
    __shared__ float s_val[MAXNZ];
    __shared__ int   s_idx[MAXNZ];
    __shared__ int   s_cnt;
    if (tid == 0) s_cnt = 0;
    __syncthreads();

    const float4* row = (const float4*)(A + (size_t)loc_t * NLOC);
    for (int i = tid; i < ROW4; i += 256) {
        float4 v = row[i];
        if (v.x != 0.f) { int p = atomicAdd(&s_cnt, 1); if (p < MAXNZ) { s_idx[p] = 4*i+0; s_val[p] = v.x; } }
        if (v.y != 0.f) { int p = atomicAdd(&s_cnt, 1); if (p < MAXNZ) { s_idx[p] = 4*i+1; s_val[p] = v.y; } }
        if (v.z != 0.f) { int p = atomicAdd(&s_cnt, 1); if (p < MAXNZ) { s_idx[p] = 4*i+2; s_val[p] = v.z; } }
        if (v.w != 0.f) { int p = atomicAdd(&s_cnt, 1); if (p < MAXNZ) { s_idx[p] = 4*i+3; s_val[p] = v.w; } }
    }
    __syncthreads();
    const int n = min(s_cnt, MAXNZ);

    float* out0 = out + (size_t)t * DSUM;                       // [B,S,256] * 16
    float* out1 = out + (size_t)NTOK * DSUM + (size_t)t * DST;  // res_yt [B,S,64]

    if (tid < DL) {
        float acc = bias[tid];
        for (int k = 0; k < n; ++k)
            acc = fmaf(s_val[k], W[(size_t)s_idx[k] * DL + tid], acc);  // W rows L2-hot
        out0[tid] = fmaxf(acc, 0.f) * 16.0f;
    } else if (tid < DL + DST) {
        const int d = tid - DL;
        out0[tid] = emb_st[(size_t)st_t * DST + d] * 16.0f;
    } else {
        const int d = tid - DL - DST;
        out0[tid] = emb_ed[(size_t)ed_t * DED + d] * 16.0f;
    }
    if (tid < DST)
        out1[tid] = emb_st[(size_t)yt_t * DST + tid];           // res_yt NOT scaled
}

extern "C" void kernel_launch(void* const* d_in, const int* in_sizes, int n_in,
                              void* d_out, int out_size, void* d_ws, size_t ws_size,
                              hipStream_t stream) {
    fused_kernel<<<NTOK, 256, 0, stream>>>((const int*)d_in[0],
                                           (const int*)d_in[1],
                                           (const int*)d_in[2],
                                           (const float*)d_in[3],
                                           (const float*)d_in[4],
                                           (const float*)d_in[5],
                                           (const float*)d_in[6],
                                           (const float*)d_in[7],
                                           (float*)d_out);
}